// Round 5
// baseline (76.414 us; speedup 1.0000x reference)
//
#include <hip/hip_runtime.h>

// Photoreceptor Rieke model: 40,000 independent nonlinear ODE chains,
// sequential over T=1000. 1 thread = 1 chain, coalesced over p.
// R5 = R4 with native ext_vector_type float4 (HIP_vector_type float4 is a
// class -> __builtin_nontemporal_store rejected it).
// R4 theory: vmem ops per 16-step chunk cut 32 -> 8 via LDS-transposed staging:
//   x:  4x global_load_dwordx4 (4 chains/lane) -> ds_write_b128 -> ds_read_b32
//   out: ds_write_b32 per step -> ds_read_b128 -> 4x NT global_store_dwordx4
// R3 analysis: 16 loads + 16 stores per phase x depth-4 = 128 wanted in flight,
// but vmcnt caps at 63 -> issue stalls; effective depth ~2. Fatter ops fix it.
#define B_ 16
#define T_ 1000
#define P_ 2500
#define NCH (B_ * P_)   // 40000 = 625 blocks * 64 threads exactly

typedef float f4 __attribute__((ext_vector_type(4)));

__device__ __forceinline__ float rcp_fast(float v) {
    return __builtin_amdgcn_rcpf(v);   // ~1 ulp, single v_rcp_f32
}

extern "C" __global__ void __launch_bounds__(64, 1)
prk_kernel(const float* __restrict__ x,
           const float* __restrict__ sigma_p,  const float* __restrict__ phi_p,
           const float* __restrict__ eta_p,    const float* __restrict__ c2c_p,
           const float* __restrict__ hill_p,   const float* __restrict__ cdark_p,
           const float* __restrict__ beta_p,   const float* __restrict__ bslow_p,
           const float* __restrict__ hcoef_p,  const float* __restrict__ haff_p,
           const float* __restrict__ gamma_p,  const float* __restrict__ gdark_p,
           float* __restrict__ out)
{
    const int lane = threadIdx.x;
    const int cid  = blockIdx.x * 64 + lane;     // own chain
    const int b_o  = cid / P_;
    const int p_o  = cid - b_o * P_;

    // loader mapping: this lane moves float4 for 4 consecutive chains
    const int colg = (lane & 15) * 4;            // col within block, 0..60
    const int rowl = lane >> 4;                  // 0..3
    const int cidL = blockIdx.x * 64 + colg;     // first chain of the quad
    const int b_l  = cidL / P_;                  // quad never straddles b (P%4==0)
    const int p_l  = cidL - b_l * P_;
    const float* __restrict__ xld  = x   + (size_t)b_l * T_ * P_ + p_l;
    float*       __restrict__ old_ = out + (size_t)b_l * T_ * P_ + p_l;

    const float sigma        = sigma_p[0];
    const float phi          = phi_p[0];
    const float eta          = eta_p[0];
    const float cgmp2cur     = c2c_p[0];
    const float cgmphill     = hill_p[0];
    const float cdark        = cdark_p[0];
    const float beta         = beta_p[0];
    const float betaSlow     = bslow_p[0];
    const float hillcoef     = hcoef_p[0];
    const float hillaffinity = haff_p[0];
    const float gamma        = gamma_p[0] * 0.125f;  // gamma / timeBin(8)
    const float gdark        = gdark_p[0];
    const float DT = 0.008f;                          // 0.001 * 8

    // derived constants (once per thread; uniform -> SGPRs)
    const float darkCurrent = powf(gdark, cgmphill) * cgmp2cur * 0.5f;
    const float gdark_ = powf(2.0f * darkCurrent / cgmp2cur, 1.0f / cgmphill);
    const float cur2ca = beta * cdark / darkCurrent;
    const float smax   = eta / phi * gdark_ *
                         (1.0f + powf(cdark / hillaffinity, hillcoef));

    const float Ar  = 1.0f - DT * sigma;
    const float Ap  = 1.0f - DT * phi;
    const float Pe  = DT * eta;
    const float Ac  = 1.0f - DT * beta;
    const float Kc  = DT * cur2ca * cgmp2cur;
    const float Acs = 1.0f - DT * betaSlow;
    const float Bcs = DT * betaSlow;
    const float inv_cd = 1.0f / cdark;
    const float inv_ha = 1.0f / hillaffinity;
    const float outk   = -0.5f * cgmp2cur;

    // initial state (per own chain)
    const float x0 = x[(size_t)b_o * T_ * P_ + p_o];
    float r  = x0 * gamma / sigma;
    float pv = (eta + r) / phi;
    float g  = gdark_;
    float s  = gdark_ * eta / phi;
    float c  = cdark;
    float cs = cdark;
    out[(size_t)b_o * T_ * P_ + p_o] = 0.0f;     // out row 0 = 0

    if (cgmphill == 3.0f && hillcoef == 4.0f) {
        __shared__ float xbuf[2][16 * 64];       // 2 x 4KB staged x chunks
        __shared__ float obuf[16 * 64];          // 4KB staged out chunk

        auto step = [&](float xt, int u) {
            float r1  = fmaf(Ar, r, gamma * xt);
            float p1  = fmaf(Ap, pv, fmaf(DT, r, Pe));
            float g3  = g * g * g;
            float den = fmaf(cs, inv_cd, 1.0f);
            float c1  = fmaf(Ac, c, Kc * g3 * rcp_fast(den));
            float cs1 = fmaf(Acs, cs, Bcs * c);
            float yy  = c1 * inv_ha;
            float y2  = yy * yy;
            float y4  = y2 * y2;
            float s1  = smax * rcp_fast(1.0f + y4);
            float g1  = fmaf(DT, fmaf(-pv, g, s), g);
            obuf[u * 64 + lane] = outk * (g1 * g1 * g1);
            r = r1; pv = p1; c = c1; cs = cs1; s = s1; g = g1;
        };

        f4 GA[4], GB[4];   // two in-flight load sets (issue-ahead = 2 phases)

#define SB __builtin_amdgcn_sched_barrier(0)
#define LOADX(G, chunk) do {                                             \
            _Pragma("unroll")                                            \
            for (int i = 0; i < 4; ++i) {                                \
                int t = 16 * (chunk) + rowl + 4 * i;                     \
                t = t > 998 ? 998 : t;                                   \
                G[i] = *(const f4*)(xld + (size_t)t * P_);               \
            }                                                            \
        } while (0)
#define STAGEX(bi, G) do {                                               \
            _Pragma("unroll")                                            \
            for (int i = 0; i < 4; ++i)                                  \
                *(f4*)&xbuf[bi][(rowl + 4 * i) * 64 + colg] = G[i];      \
        } while (0)
#define COMPUTE(chunk, bi, nst) do {                                     \
            _Pragma("unroll")                                            \
            for (int u = 0; u < (nst); ++u)                              \
                step(xbuf[bi][u * 64 + lane], u);                        \
        } while (0)
#define FLUSH(chunk, nrow) do {                                          \
            _Pragma("unroll")                                            \
            for (int i = 0; i < 4; ++i) {                                \
                int rr = rowl + 4 * i;                                   \
                if (rr < (nrow)) {                                       \
                    f4 v = *(const f4*)&obuf[rr * 64 + colg];            \
                    __builtin_nontemporal_store(v,                       \
                        (f4*)(old_ + (size_t)(16 * (chunk) + 1 + rr) * P_)); \
                }                                                        \
            }                                                            \
        } while (0)

        // prologue: c0->GA, c1->GB, stage c0, c2->GA
        LOADX(GA, 0); SB;
        LOADX(GB, 1); SB;
        STAGEX(0, GA);               // vmcnt-wait on GA happens here
        LOADX(GA, 2); SB;

        // main loop: phase p computes chunk p; stages chunk p+1; issues p+3.
        // Unrolled x2 so reg-set/LDS-buffer parity is compile-time.
        #pragma unroll 1
        for (int p = 0; p < 60; p += 2) {
            STAGEX(1, GB);           // stage chunk p+1 (issued 2 phases ago)
            LOADX(GB, p + 3); SB;    // issue chunk p+3
            COMPUTE(p, 0, 16);       // compute chunk p from xbuf0
            FLUSH(p, 16);
            STAGEX(0, GA);           // stage chunk p+2
            LOADX(GA, p + 4); SB;    // issue chunk p+4
            COMPUTE(p + 1, 1, 16);   // compute chunk p+1 from xbuf1
            FLUSH(p + 1, 16);
        }
        // epilogue: GB holds c61, GA holds c62 (issued at p=58)
        STAGEX(1, GB);
        COMPUTE(60, 0, 16); FLUSH(60, 16);
        STAGEX(0, GA);
        COMPUTE(61, 1, 16); FLUSH(61, 16);
        COMPUTE(62, 0, 7);  FLUSH(62, 7);   // steps 992..998 -> rows 993..999

#undef SB
#undef LOADX
#undef STAGEX
#undef COMPUTE
#undef FLUSH
    } else {
        // ---- generic fallback (exact powf; never taken for bench params) ----
        const float* __restrict__ xp = x   + (size_t)b_o * T_ * P_ + p_o;
        float*       __restrict__ op = out + (size_t)b_o * T_ * P_ + p_o;
        for (int t = 0; t < T_ - 1; ++t) {
            float xt  = xp[(size_t)t * P_];
            float r1  = r + DT * (-sigma * r) + gamma * xt;
            float p1  = pv + DT * (r + eta - phi * pv);
            float c1  = c + DT * (cur2ca * cgmp2cur * powf(g, cgmphill) /
                                  (1.0f + cs / cdark) - beta * c);
            float cs1 = cs - DT * (betaSlow * (cs - c));
            float s1  = smax / (1.0f + powf(c1 / hillaffinity, hillcoef));
            float g1  = g + DT * (s - pv * g);
            op[(size_t)(t + 1) * P_] = -(cgmp2cur * powf(g1, cgmphill)) * 0.5f;
            r = r1; pv = p1; c = c1; cs = cs1; s = s1; g = g1;
        }
    }
}

extern "C" void kernel_launch(void* const* d_in, const int* in_sizes, int n_in,
                              void* d_out, int out_size, void* d_ws, size_t ws_size,
                              hipStream_t stream) {
    const float* x = (const float*)d_in[0];
    prk_kernel<<<dim3(NCH / 64), dim3(64), 0, stream>>>(
        x,
        (const float*)d_in[1],  (const float*)d_in[2],  (const float*)d_in[3],
        (const float*)d_in[4],  (const float*)d_in[5],  (const float*)d_in[6],
        (const float*)d_in[7],  (const float*)d_in[8],  (const float*)d_in[9],
        (const float*)d_in[10], (const float*)d_in[11], (const float*)d_in[12],
        (float*)d_out);
}